// Round 2
// baseline (391.449 us; speedup 1.0000x reference)
//
#include <hip/hip_runtime.h>

// Problem constants
#define Bq 16
#define Cq 512
#define Nq 4096
#define Hq 512

// ---------------------------------------------------------------------------
// K1: xs_n[b,n] = sum_c x[b,c,n]   (part A: blocks [0,256), atomic over 4 c-chunks)
//     xs_c[b,c] = sum_n x[b,c,n]   (part B: blocks [256,256+8192), block per (b,c))
// ---------------------------------------------------------------------------
__global__ __launch_bounds__(256) void k1_xs(const float* __restrict__ x,
                                             float* __restrict__ xs_n,
                                             float* __restrict__ xs_c){
  __shared__ float lds[4];
  int blk = blockIdx.x;
  if (blk < Bq*4*4) {
    int b  = blk >> 4;
    int r  = blk & 15;
    int nc = r >> 2;        // 4 n-chunks of 1024
    int cc = r & 3;         // 4 c-chunks of 128
    int n0 = nc*1024 + (int)threadIdx.x*4;
    const float4* px = (const float4*)(x + ((size_t)b*Cq + (size_t)cc*128)*Nq + n0);
    float4 acc = {0.f,0.f,0.f,0.f};
    #pragma unroll 4
    for (int c = 0; c < 128; ++c){
      float4 v = *px; px += Nq/4;
      acc.x += v.x; acc.y += v.y; acc.z += v.z; acc.w += v.w;
    }
    float* dst = xs_n + (size_t)b*Nq + n0;
    atomicAdd(dst+0, acc.x); atomicAdd(dst+1, acc.y);
    atomicAdd(dst+2, acc.z); atomicAdd(dst+3, acc.w);
  } else {
    int blk2 = blk - Bq*4*4;
    int b = blk2 >> 9;
    int c = blk2 & 511;
    const float4* row = (const float4*)(x + ((size_t)b*Cq + c)*Nq);
    float acc = 0.f;
    #pragma unroll
    for (int s = 0; s < 4; ++s){
      float4 v = row[s*256 + threadIdx.x];
      acc += (v.x + v.y) + (v.z + v.w);
    }
    #pragma unroll
    for (int off=32; off; off>>=1) acc += __shfl_down(acc, off, 64);
    if ((threadIdx.x & 63) == 0) lds[threadIdx.x >> 6] = acc;
    __syncthreads();
    if (threadIdx.x == 0) xs_c[b*Cq + c] = (lds[0]+lds[1])+(lds[2]+lds[3]);
  }
}

// ---------------------------------------------------------------------------
// K2: s_cf[b,h] = sum_n xs_n[b,n]*w_cf[h,n]   (blocks [0,512))
//     s_sf[b,h] = sum_c xs_c[b,c]*w_sf[h,c]   (blocks [512,1024))
// ---------------------------------------------------------------------------
__global__ __launch_bounds__(256) void k2_s(const float* __restrict__ w_cf,
                                            const float* __restrict__ w_sf,
                                            const float* __restrict__ xs_n,
                                            const float* __restrict__ xs_c,
                                            float* __restrict__ s_cf,
                                            float* __restrict__ s_sf){
  __shared__ float lds[4];
  int blk = blockIdx.x;
  const float* w; const float* src; float* dst; int L;
  if (blk < Hq) { w = w_cf + (size_t)blk*Nq; src = xs_n; dst = s_cf; L = Nq; }
  else          { w = w_sf + (size_t)(blk-Hq)*Cq; src = xs_c; dst = s_sf; L = Cq; }
  int h = blk & (Hq-1);
  float acc[Bq];
  #pragma unroll
  for (int b=0;b<Bq;b++) acc[b]=0.f;
  for (int i = threadIdx.x; i < L; i += 256){
    float wv = w[i];
    #pragma unroll
    for (int b=0;b<Bq;b++) acc[b] += wv * src[b*L + i];
  }
  #pragma unroll
  for (int b=0;b<Bq;b++){
    float v = acc[b];
    #pragma unroll
    for (int off=32; off; off>>=1) v += __shfl_down(v, off, 64);
    if ((threadIdx.x & 63)==0) lds[threadIdx.x>>6] = v;
    __syncthreads();
    if (threadIdx.x==0) dst[b*Hq + h] = (lds[0]+lds[1])+(lds[2]+lds[3]);
    __syncthreads();
  }
}

// ---------------------------------------------------------------------------
// K3: v_cg[b,n] = sum_h s_cf[b,h]*w_cg[h,n]  (blocks [0,128): 16 j-chunks x 8 h-chunks)
//     v_sg[b,c] = sum_h s_sf[b,h]*w_sg[h,c]  (blocks [128,144): 2 j-chunks x 8 h-chunks)
// Atomic accumulate over h-chunks (dst pre-zeroed).
// ---------------------------------------------------------------------------
__global__ __launch_bounds__(256) void k3_v(const float* __restrict__ w_cg,
                                            const float* __restrict__ w_sg,
                                            const float* __restrict__ s_cf,
                                            const float* __restrict__ s_sf,
                                            float* __restrict__ v_cg,
                                            float* __restrict__ v_sg){
  __shared__ float sl[Bq*64];
  int blk = blockIdx.x;
  const float* w; const float* s; float* dst; int L, jc, hc;
  if (blk < 128){ w=w_cg; s=s_cf; dst=v_cg; L=Nq; jc=blk>>3; hc=blk&7; }
  else { int k=blk-128; w=w_sg; s=s_sf; dst=v_sg; L=Cq; jc=k>>3; hc=k&7; }
  int h0 = hc*64;
  for (int i = threadIdx.x; i < Bq*64; i += 256){
    int b = i >> 6, hh = i & 63;
    sl[i] = s[b*Hq + h0 + hh];
  }
  __syncthreads();
  int j = (jc<<8) + (int)threadIdx.x;
  float acc[Bq];
  #pragma unroll
  for (int b=0;b<Bq;b++) acc[b]=0.f;
  for (int hh=0; hh<64; ++hh){
    float wv = w[(size_t)(h0+hh)*L + j];
    #pragma unroll
    for (int b=0;b<Bq;b++) acc[b] += sl[b*64+hh]*wv;
  }
  #pragma unroll
  for (int b=0;b<Bq;b++) atomicAdd(&dst[b*L + j], acc[b]);
}

// ---------------------------------------------------------------------------
// K4: sp_comp[b,n] = sum_c x[b,c,n]*v_sg[b,c]  (part A, atomic over c-chunks)
//     ch_comp[b,c] = sum_n x[b,c,n]*v_cg[b,n]  (part B, block per (b,c))
// ---------------------------------------------------------------------------
__global__ __launch_bounds__(256) void k4_comp(const float* __restrict__ x,
                                               const float* __restrict__ v_cg,
                                               const float* __restrict__ v_sg,
                                               float* __restrict__ sp,
                                               float* __restrict__ ch){
  __shared__ float lds[4];
  int blk = blockIdx.x;
  if (blk < Bq*4*4){
    int b = blk >> 4; int r = blk & 15; int nc = r>>2; int cc = r&3;
    int n0 = nc*1024 + (int)threadIdx.x*4;
    const float4* px = (const float4*)(x + ((size_t)b*Cq + (size_t)cc*128)*Nq + n0);
    const float* vs = v_sg + b*Cq + cc*128;
    float4 acc = {0.f,0.f,0.f,0.f};
    #pragma unroll 4
    for (int c=0;c<128;++c){
      float4 v = *px; px += Nq/4;
      float s = vs[c];
      acc.x += v.x*s; acc.y += v.y*s; acc.z += v.z*s; acc.w += v.w*s;
    }
    float* dst = sp + (size_t)b*Nq + n0;
    atomicAdd(dst+0, acc.x); atomicAdd(dst+1, acc.y);
    atomicAdd(dst+2, acc.z); atomicAdd(dst+3, acc.w);
  } else {
    int blk2 = blk - Bq*4*4;
    int b = blk2 >> 9; int c = blk2 & 511;
    const float4* row = (const float4*)(x + ((size_t)b*Cq + c)*Nq);
    const float4* vg = (const float4*)(v_cg + (size_t)b*Nq);
    float acc=0.f;
    #pragma unroll
    for (int s=0;s<4;++s){
      float4 xv = row[s*256 + threadIdx.x];
      float4 vv = vg [s*256 + threadIdx.x];
      acc += xv.x*vv.x + xv.y*vv.y + xv.z*vv.z + xv.w*vv.w;
    }
    #pragma unroll
    for (int off=32; off; off>>=1) acc += __shfl_down(acc, off, 64);
    if ((threadIdx.x&63)==0) lds[threadIdx.x>>6]=acc;
    __syncthreads();
    if (threadIdx.x==0) ch[b*Cq+c] = (lds[0]+lds[1])+(lds[2]+lds[3]);
  }
}

// ---------------------------------------------------------------------------
// K5: softmax rows. blocks [0,16): channel (L=512); [16,32): spatial (L=4096).
// Writes fp32 masks directly into the d_out tail (return order: out, cm, sm).
// ---------------------------------------------------------------------------
__global__ __launch_bounds__(256) void k5_softmax(const float* __restrict__ ch,
                                                  const float* __restrict__ sp,
                                                  float* __restrict__ out){
  __shared__ float lds[4];
  __shared__ float bcast;
  int blk = blockIdx.x;
  const float* src; float* dst; int L;
  const size_t OUT0 = (size_t)Bq*Cq*Nq;
  if (blk < Bq){ int b=blk;    src=ch+(size_t)b*Cq; dst=out+OUT0+(size_t)b*Cq; L=Cq; }
  else         { int b=blk-Bq; src=sp+(size_t)b*Nq; dst=out+OUT0+(size_t)Bq*Cq+(size_t)b*Nq; L=Nq; }
  float m = -3.4e38f;
  for (int i=threadIdx.x;i<L;i+=256) m = fmaxf(m, src[i]);
  #pragma unroll
  for (int off=32; off; off>>=1) m = fmaxf(m, __shfl_down(m, off, 64));
  if ((threadIdx.x&63)==0) lds[threadIdx.x>>6]=m;
  __syncthreads();
  if (threadIdx.x==0) bcast = fmaxf(fmaxf(lds[0],lds[1]),fmaxf(lds[2],lds[3]));
  __syncthreads();
  m = bcast;
  float ssum=0.f;
  for (int i=threadIdx.x;i<L;i+=256) ssum += __expf(src[i]-m);
  #pragma unroll
  for (int off=32; off; off>>=1) ssum += __shfl_down(ssum, off, 64);
  __syncthreads();
  if ((threadIdx.x&63)==0) lds[threadIdx.x>>6]=ssum;
  __syncthreads();
  if (threadIdx.x==0) bcast = 1.f/((lds[0]+lds[1])+(lds[2]+lds[3]));
  __syncthreads();
  float inv = bcast;
  for (int i=threadIdx.x;i<L;i+=256) dst[i] = __expf(src[i]-m)*inv;
}

// ---------------------------------------------------------------------------
// K6: out[b,c,n] = x[b,c,n] * cm[b,c] * sm[b,n]   (float4)
// grid: B*C*4 blocks; block (b,c,quarter); 256 thr x float4 = 1024 elems
// ---------------------------------------------------------------------------
__global__ __launch_bounds__(256) void k6_out(const float* __restrict__ x,
                                              float* __restrict__ out){
  const size_t OUT0 = (size_t)Bq*Cq*Nq;
  const float* cm = out + OUT0;
  const float* sm = out + OUT0 + (size_t)Bq*Cq;
  int blk = blockIdx.x;
  int b = blk >> 11;
  int r = blk & 2047;
  int c = r >> 2;
  int q = r & 3;
  size_t rowoff = ((size_t)b*Cq + c)*Nq;
  int n0 = q*1024 + (int)threadIdx.x*4;
  float4 xv = *(const float4*)(x + rowoff + n0);
  float4 sv = *(const float4*)(sm + (size_t)b*Nq + n0);
  float cmv = cm[b*Cq + c];
  float4 o;
  o.x = xv.x*cmv*sv.x; o.y = xv.y*cmv*sv.y;
  o.z = xv.z*cmv*sv.z; o.w = xv.w*cmv*sv.w;
  *(float4*)(out + rowoff + n0) = o;
}

extern "C" void kernel_launch(void* const* d_in, const int* in_sizes, int n_in,
                              void* d_out, int out_size, void* d_ws, size_t ws_size,
                              hipStream_t stream){
  const float* x    = (const float*)d_in[0];
  const float* w_cf = (const float*)d_in[1];
  const float* w_cg = (const float*)d_in[2];
  const float* w_sf = (const float*)d_in[3];
  const float* w_sg = (const float*)d_in[4];
  float* out = (float*)d_out;

  float* ws   = (float*)d_ws;
  float* xs_n = ws;                    // B*N = 65536
  float* xs_c = xs_n + Bq*Nq;          // B*C = 8192
  float* s_cf = xs_c + Bq*Cq;          // B*H = 8192
  float* s_sf = s_cf + Bq*Hq;          // B*H = 8192
  float* v_cg = s_sf + Bq*Hq;          // B*N = 65536
  float* v_sg = v_cg + Bq*Nq;          // B*C = 8192
  float* chc  = v_sg + Bq*Cq;          // B*C = 8192
  float* spc  = chc  + Bq*Cq;          // B*N = 65536

  size_t zbytes = (size_t)((spc + Bq*Nq) - ws) * sizeof(float);
  if (zbytes > ws_size) zbytes = ws_size;
  hipMemsetAsync(d_ws, 0, zbytes, stream);

  k1_xs     <<<Bq*4*4 + Bq*Cq, 256, 0, stream>>>(x, xs_n, xs_c);
  k2_s      <<<2*Hq,           256, 0, stream>>>(w_cf, w_sf, xs_n, xs_c, s_cf, s_sf);
  k3_v      <<<144,            256, 0, stream>>>(w_cg, w_sg, s_cf, s_sf, v_cg, v_sg);
  k4_comp   <<<Bq*4*4 + Bq*Cq, 256, 0, stream>>>(x, v_cg, v_sg, spc, chc);
  k5_softmax<<<2*Bq,           256, 0, stream>>>(chc, spc, out);
  k6_out    <<<Bq*Cq*4,        256, 0, stream>>>(x, out);
}